// Round 1
// baseline (409.697 us; speedup 1.0000x reference)
//
#include <hip/hip_runtime.h>

// ---------------------------------------------------------------------------
// YOLO NMS post-processing for MI355X.
// Pipeline: scores+hist -> bucket select -> compact -> bitonic sort (4096 of
// 8192) -> gather boxes -> 64x64 IoU bitmask -> single-wave greedy scan with
// early-exit at 300 keeps -> gather outputs.
// All IoU-relevant fp32 math uses _rn intrinsics so hipcc's default
// -ffp-contract=fast cannot fuse mul+add into fma (must match numpy fp32).
// ---------------------------------------------------------------------------

constexpr int    N_ANCH = 100800;
constexpr int    DIMV   = 117;   // 4 box + 1 obj + 80 cls + 32 mask
constexpr int    NCLS   = 80;
constexpr int    TOPKN  = 4096;
constexpr int    MAXDET = 300;

// workspace layout (bytes)
constexpr size_t WS_HIST   = 0;                          // 65536 u32
constexpr size_t WS_SCORES = WS_HIST   + 65536ull * 4;   // 100800 f32
constexpr size_t WS_CLS    = WS_SCORES + 100800ull * 4;  // 100800 i32
constexpr size_t WS_SEL    = WS_CLS    + 100800ull * 4;  // 64 i32: [0]=B [1]=cntAbove [2]=nA [3]=nB
constexpr size_t WS_ARRA   = WS_SEL    + 256;            // 8192 u64
constexpr size_t WS_ARRB   = WS_ARRA   + 8192ull * 8;    // 8192 u64
constexpr size_t WS_SIDX   = WS_ARRB   + 8192ull * 8;    // 4096 i32  (anchor id per sorted slot)
constexpr size_t WS_SSC    = WS_SIDX   + 4096ull * 4;    // 4096 f32  (sorted scores desc)
constexpr size_t WS_BOXES  = WS_SSC    + 4096ull * 4;    // 4096*4 f32 (y1 x1 y2 x2)
constexpr size_t WS_MASK   = WS_BOXES  + 4096ull * 16;   // 4096*64 u64 suppression bitmask
constexpr size_t WS_OUTI   = WS_MASK   + 4096ull * 64 * 8; // 300 i32
constexpr size_t WS_OUTS   = WS_OUTI   + 1200;           // 300 f32

__global__ void zero_kernel(unsigned* __restrict__ hist, int* __restrict__ sel) {
    int i = blockIdx.x * blockDim.x + threadIdx.x;
    if (i < 65536) hist[i] = 0u;
    if (i < 64)    sel[i]  = 0;
}

// per-anchor score = max_c(cls[c]*obj), class = first argmax; histogram top-16
// bits of the fp32 pattern (all candidate scores are positive -> bit pattern
// order == numeric order).
__global__ void score_kernel(const float* __restrict__ x, float* __restrict__ scores,
                             int* __restrict__ cls, unsigned* __restrict__ hist) {
    int a = blockIdx.x * blockDim.x + threadIdx.x;
    if (a >= N_ANCH) return;
    const float* p = x + (size_t)a * DIMV;
    float obj = p[4];
    float best = -1.0f;
    int   bc   = 0;
#pragma unroll 4
    for (int c = 0; c < NCLS; ++c) {
        float s = __fmul_rn(p[5 + c], obj);
        if (s > best) { best = s; bc = c; }   // strict > keeps lowest class on ties
    }
    bool valid = obj > 0.25f;
    scores[a] = valid ? best : -1.0f;
    cls[a]    = bc;
    if (valid) atomicAdd(&hist[__float_as_uint(best) >> 16], 1u);
}

// find bucket B such that count(bucket > B) < 4096 <= count(bucket >= B)
__global__ void select_kernel(const unsigned* __restrict__ hist, int* sel) {
    __shared__ unsigned sv[1024];
    __shared__ int found;
    int tid = threadIdx.x;
    if (tid == 0) found = -1;
    __syncthreads();
    unsigned running = 0;
    for (int chunk = 15; chunk >= 0; --chunk) {      // scores < 2.0 -> bucket <= 16383
        int b = chunk * 1024 + (1023 - tid);         // ascending tid == descending bucket
        unsigned v = hist[b];
        sv[tid] = v;
        __syncthreads();
        for (int off = 1; off < 1024; off <<= 1) {   // inclusive Hillis-Steele scan
            unsigned t = (tid >= off) ? sv[tid - off] : 0u;
            __syncthreads();
            sv[tid] += t;
            __syncthreads();
        }
        unsigned incl = sv[tid];
        unsigned excl = incl - v;
        unsigned total = sv[1023];
        if (found < 0 && running + incl >= (unsigned)TOPKN && running + excl < (unsigned)TOPKN) {
            sel[0] = b;
            sel[1] = (int)(running + excl);
            found = 1;
        }
        __syncthreads();
        if (found >= 0) break;
        running += total;
    }
}

// key = (score_bits << 32) | ~anchor  -> descending key == (score desc, idx asc)
__global__ void compact_kernel(const float* __restrict__ scores, int* sel,
                               unsigned long long* __restrict__ arrA,
                               unsigned long long* __restrict__ arrB) {
    int a = blockIdx.x * blockDim.x + threadIdx.x;
    if (a >= N_ANCH) return;
    float s = scores[a];
    if (s < 0.0f) return;
    unsigned bits = __float_as_uint(s);
    int b = (int)(bits >> 16);
    int B = sel[0];
    if (b < B) return;
    unsigned long long key = ((unsigned long long)bits << 32) | (unsigned)(~a);
    if (b > B) {
        int pos = atomicAdd(&sel[2], 1);
        if (pos < 8192) arrA[pos] = key;
    } else {
        int pos = atomicAdd(&sel[3], 1);
        if (pos < 8192) arrB[pos] = key;
    }
}

// bitonic sort 8192 u64 keys descending in LDS; emit first 4096.
__global__ void sort_kernel(const int* sel, const unsigned long long* __restrict__ arrA,
                            const unsigned long long* __restrict__ arrB,
                            int* __restrict__ sidx, float* __restrict__ sscore) {
    __shared__ unsigned long long sm[8192];
    int tid = threadIdx.x;
    int nA = sel[2]; if (nA > 8192) nA = 8192;
    int nB = sel[3]; if (nB > 8192 - nA) nB = 8192 - nA;
    for (int i = tid; i < 8192; i += 1024) {
        unsigned long long k = 0ull;
        if (i < nA)           k = arrA[i];
        else if (i < nA + nB) k = arrB[i - nA];
        sm[i] = k;
    }
    __syncthreads();
    for (unsigned k = 2; k <= 8192; k <<= 1) {
        for (unsigned j = k >> 1; j > 0; j >>= 1) {
            for (unsigned i = tid; i < 8192; i += 1024) {
                unsigned ixj = i ^ j;
                if (ixj > i) {
                    unsigned long long va = sm[i], vb = sm[ixj];
                    bool sw = ((i & k) == 0) ? (va < vb) : (va > vb); // overall descending
                    if (sw) { sm[i] = vb; sm[ixj] = va; }
                }
            }
            __syncthreads();
        }
    }
    for (int s = tid; s < TOPKN; s += 1024) {
        unsigned long long kk = sm[s];
        sidx[s]   = (int)(~(unsigned)(kk & 0xFFFFFFFFull));
        sscore[s] = __uint_as_float((unsigned)(kk >> 32));
    }
}

// convert xc,yc,w,h -> y1,x1,y2,x2 for the sorted 4096 (no fma; match numpy)
__global__ void boxes_kernel(const float* __restrict__ x, const int* __restrict__ sidx,
                             float* __restrict__ boxes) {
    int s = blockIdx.x * blockDim.x + threadIdx.x;
    if (s >= TOPKN) return;
    int a = sidx[s];
    const float* p = x + (size_t)a * DIMV;
    float xc = p[0], yc = p[1], w = p[2], h = p[3];
    float hw = __fmul_rn(w, 0.5f);
    float hh = __fmul_rn(h, 0.5f);
    boxes[s * 4 + 0] = __fsub_rn(yc, hh);
    boxes[s * 4 + 1] = __fsub_rn(xc, hw);
    boxes[s * 4 + 2] = __fadd_rn(yc, hh);
    boxes[s * 4 + 3] = __fadd_rn(xc, hw);
}

// 64x64 tile IoU bitmask: bit j of mask[r][colT] set iff iou(r, colT*64+j)>0.45 && j_global>r
__global__ void iou_mask_kernel(const float* __restrict__ boxes,
                                unsigned long long* __restrict__ mask) {
    int colT = blockIdx.x, rowT = blockIdx.y;
    int t = threadIdx.x;                 // 0..63
    int r = rowT * 64 + t;
    if (colT < rowT) {                   // whole tile has j < r
        mask[(size_t)r * 64 + colT] = 0ull;
        return;
    }
    __shared__ float cb[64][5];
    int cj = colT * 64 + t;
    {
        float y1 = boxes[cj * 4 + 0], x1 = boxes[cj * 4 + 1];
        float y2 = boxes[cj * 4 + 2], x2 = boxes[cj * 4 + 3];
        cb[t][0] = y1; cb[t][1] = x1; cb[t][2] = y2; cb[t][3] = x2;
        cb[t][4] = __fmul_rn(__fsub_rn(y2, y1), __fsub_rn(x2, x1));
    }
    __syncthreads();
    float ry1 = boxes[r * 4 + 0], rx1 = boxes[r * 4 + 1];
    float ry2 = boxes[r * 4 + 2], rx2 = boxes[r * 4 + 3];
    float rarea = __fmul_rn(__fsub_rn(ry2, ry1), __fsub_rn(rx2, rx1));
    unsigned long long bitsw = 0ull;
#pragma unroll 8
    for (int j = 0; j < 64; ++j) {
        float iy1 = fmaxf(ry1, cb[j][0]);
        float ix1 = fmaxf(rx1, cb[j][1]);
        float iy2 = fminf(ry2, cb[j][2]);
        float ix2 = fminf(rx2, cb[j][3]);
        float ih = fmaxf(__fsub_rn(iy2, iy1), 0.0f);
        float iw = fmaxf(__fsub_rn(ix2, ix1), 0.0f);
        float inter = __fmul_rn(ih, iw);
        float uni = __fsub_rn(__fadd_rn(rarea, cb[j][4]), inter);
        float iou = __fdiv_rn(inter, fmaxf(uni, 1e-9f));
        if (iou > 0.45f && (colT * 64 + j) > r) bitsw |= (1ull << j);
    }
    mask[(size_t)r * 64 + colT] = bitsw;
}

// single-wave sequential greedy scan. lane j owns suppression word j.
// Early-exit at 300 keeps (exact: output is the first 300 kept rows).
// If K<300, pad with lowest-index suppressed rows at score -1 (== stable
// top_k of where(keep, s, -1)).
__global__ void nms_scan_kernel(const unsigned long long* __restrict__ mask,
                                const float* __restrict__ sscore,
                                int* __restrict__ outIdx, float* __restrict__ outScore) {
    int lane = threadIdx.x;              // 64 threads = one wave
    unsigned long long remv = 0ull;
    __shared__ int keepArr[MAXDET];
    __shared__ unsigned long long remvFinal[64];
    int count = 0;
    for (int w = 0; w < 64 && count < MAXDET; ++w) {
        unsigned long long cur = __shfl(remv, w);
        int pos = 0;
        while (pos < 64) {
            unsigned long long avail = (~cur) & (~0ull << pos);
            if (!avail) break;
            int b = (int)__builtin_ctzll(avail);
            int i = (w << 6) + b;
            if (lane == 0) keepArr[count] = i;
            count++;
            if (count >= MAXDET) break;
            remv |= mask[(size_t)i * 64 + lane];
            cur = __shfl(remv, w);
            pos = b + 1;
        }
    }
    remvFinal[lane] = remv;
    __syncthreads();
    int K = count;                       // uniform across the wave
    for (int k = lane; k < K; k += 64) {
        int s = keepArr[k];
        outIdx[k] = s;
        outScore[k] = sscore[s];
    }
    if (K < MAXDET && lane == 0) {
        int filled = K;
        for (int w = 0; w < 64 && filled < MAXDET; ++w) {
            unsigned long long word = remvFinal[w];
            while (word && filled < MAXDET) {
                int b = (int)__builtin_ctzll(word);
                word &= word - 1;
                outIdx[filled] = (w << 6) + b;
                outScore[filled] = -1.0f;
                filled++;
            }
        }
    }
}

// emit: boxes[300*4] | classes[300] | scores[300] | masks[300*32]
__global__ void write_out_kernel(const float* __restrict__ x, const int* __restrict__ sidx,
                                 const int* __restrict__ cls, const float* __restrict__ boxes,
                                 const int* __restrict__ outIdx, const float* __restrict__ outScore,
                                 float* __restrict__ out) {
    int o = blockIdx.x;                  // 300
    int t = threadIdx.x;                 // 64
    int s = outIdx[o];
    int a = sidx[s];
    if (t < 32) {
        out[1800 + o * 32 + t] = x[(size_t)a * DIMV + 85 + t];
    } else if (t < 36) {
        out[o * 4 + (t - 32)] = boxes[s * 4 + (t - 32)];
    } else if (t == 36) {
        out[1200 + o] = (float)cls[a];
    } else if (t == 37) {
        out[1500 + o] = outScore[o];
    }
}

extern "C" void kernel_launch(void* const* d_in, const int* in_sizes, int n_in,
                              void* d_out, int out_size, void* d_ws, size_t ws_size,
                              hipStream_t stream) {
    const float* x = (const float*)d_in[0];
    char* ws = (char*)d_ws;
    unsigned*            hist   = (unsigned*)(ws + WS_HIST);
    float*               scores = (float*)(ws + WS_SCORES);
    int*                 cls    = (int*)(ws + WS_CLS);
    int*                 sel    = (int*)(ws + WS_SEL);
    unsigned long long*  arrA   = (unsigned long long*)(ws + WS_ARRA);
    unsigned long long*  arrB   = (unsigned long long*)(ws + WS_ARRB);
    int*                 sidx   = (int*)(ws + WS_SIDX);
    float*               sscore = (float*)(ws + WS_SSC);
    float*               boxes  = (float*)(ws + WS_BOXES);
    unsigned long long*  mask   = (unsigned long long*)(ws + WS_MASK);
    int*                 outIdx = (int*)(ws + WS_OUTI);
    float*               outSc  = (float*)(ws + WS_OUTS);

    zero_kernel<<<(65536 + 255) / 256, 256, 0, stream>>>(hist, sel);
    score_kernel<<<(N_ANCH + 255) / 256, 256, 0, stream>>>(x, scores, cls, hist);
    select_kernel<<<1, 1024, 0, stream>>>(hist, sel);
    compact_kernel<<<(N_ANCH + 255) / 256, 256, 0, stream>>>(scores, sel, arrA, arrB);
    sort_kernel<<<1, 1024, 0, stream>>>(sel, arrA, arrB, sidx, sscore);
    boxes_kernel<<<(TOPKN + 255) / 256, 256, 0, stream>>>(x, sidx, boxes);
    dim3 mg(64, 64);
    iou_mask_kernel<<<mg, 64, 0, stream>>>(boxes, mask);
    nms_scan_kernel<<<1, 64, 0, stream>>>(mask, sscore, outIdx, outSc);
    write_out_kernel<<<MAXDET, 64, 0, stream>>>(x, sidx, cls, boxes, outIdx, outSc, (float*)d_out);
}

// Round 2
// 333.049 us; speedup vs baseline: 1.2301x; 1.2301x over previous
//
#include <hip/hip_runtime.h>

// ---------------------------------------------------------------------------
// YOLO NMS post-processing for MI355X.
// Pipeline: scores+hist -> bucket select -> compact candidates (bucket >= B)
// -> exact rank-by-counting (replaces single-block bitonic sort; ranks of the
// unique u64 keys ARE the stable sorted positions) -> scatter by rank (+box
// decode) -> 64x64 IoU bitmask -> single-wave greedy scan, early-exit at 300
// keeps -> gather outputs.
// All IoU-relevant fp32 math uses _rn intrinsics so hipcc's default
// -ffp-contract=fast cannot fuse mul+add into fma (must match numpy fp32).
// ---------------------------------------------------------------------------

constexpr int    N_ANCH = 100800;
constexpr int    DIMV   = 117;   // 4 box + 1 obj + 80 cls + 32 mask
constexpr int    NCLS   = 80;
constexpr int    TOPKN  = 4096;
constexpr int    MAXDET = 300;
constexpr int    KCAP   = 12288; // candidate capacity (expected ~4096+|bucket B|)

// workspace layout (bytes)
constexpr size_t WS_HIST   = 0;                           // 65536 u32
constexpr size_t WS_SCORES = WS_HIST   + 65536ull * 4;    // 100800 f32
constexpr size_t WS_CLS    = WS_SCORES + 100800ull * 4;   // 100800 i32
constexpr size_t WS_SEL    = WS_CLS    + 100800ull * 4;   // 64 i32: [0]=B [1]=cntAbove [2]=nKeys
constexpr size_t WS_KEYS   = WS_SEL    + 256;             // 12288 u64
constexpr size_t WS_RANK   = WS_KEYS   + (size_t)KCAP * 8;// 12288 i32
constexpr size_t WS_SIDX   = WS_RANK   + (size_t)KCAP * 4;// 4096 i32 (anchor id / sorted slot)
constexpr size_t WS_SSC    = WS_SIDX   + 4096ull * 4;     // 4096 f32 (sorted scores desc)
constexpr size_t WS_BOXES  = WS_SSC    + 4096ull * 4;     // 4096*4 f32 (y1 x1 y2 x2)
constexpr size_t WS_MASK   = WS_BOXES  + 4096ull * 16;    // 4096*64 u64 suppression bitmask
constexpr size_t WS_OUTI   = WS_MASK   + 4096ull * 64 * 8;// 300 i32
constexpr size_t WS_OUTS   = WS_OUTI   + 1200;            // 300 f32

__global__ void zero_kernel(unsigned* __restrict__ hist, int* __restrict__ sel,
                            int* __restrict__ rank) {
    int i = blockIdx.x * blockDim.x + threadIdx.x;
    if (i < 65536) hist[i] = 0u;
    if (i < KCAP)  rank[i] = 0;
    if (i < 64)    sel[i]  = 0;
}

// per-anchor score = max_c(cls[c]*obj), class = first argmax; histogram top-16
// bits of the fp32 pattern (all candidate scores positive -> bit order ==
// numeric order).
__global__ void score_kernel(const float* __restrict__ x, float* __restrict__ scores,
                             int* __restrict__ cls, unsigned* __restrict__ hist) {
    int a = blockIdx.x * blockDim.x + threadIdx.x;
    if (a >= N_ANCH) return;
    const float* p = x + (size_t)a * DIMV;
    float obj = p[4];
    float best = -1.0f;
    int   bc   = 0;
#pragma unroll 4
    for (int c = 0; c < NCLS; ++c) {
        float s = __fmul_rn(p[5 + c], obj);
        if (s > best) { best = s; bc = c; }   // strict > keeps lowest class on ties
    }
    bool valid = obj > 0.25f;
    scores[a] = valid ? best : -1.0f;
    cls[a]    = bc;
    if (valid) atomicAdd(&hist[__float_as_uint(best) >> 16], 1u);
}

// find bucket B: cntAbove(B) < 4096 <= cntAbove(B) + hist[B].
// One pass: thread t sums a 64-bucket chunk (chunks ordered descending),
// single 1024-wide scan, crossing thread walks its chunk.
__global__ void select_kernel(const unsigned* __restrict__ hist, int* sel) {
    __shared__ unsigned sv[1024];
    int t = threadIdx.x;
    int base = 65536 - 64 * (t + 1);          // chunk t covers [base, base+63], t=0 = top
    unsigned own = 0;
#pragma unroll 8
    for (int k = 0; k < 64; ++k) own += hist[base + k];
    sv[t] = own;
    __syncthreads();
    for (int off = 1; off < 1024; off <<= 1) { // inclusive scan (descending-chunk order)
        unsigned v = (t >= off) ? sv[t - off] : 0u;
        __syncthreads();
        sv[t] += v;
        __syncthreads();
    }
    unsigned incl = sv[t];
    unsigned before = incl - own;
    if (before < (unsigned)TOPKN && incl >= (unsigned)TOPKN) {
        unsigned running = before;
        for (int k = 63; k >= 0; --k) {        // walk buckets descending
            unsigned h = hist[base + k];
            running += h;
            if (running >= (unsigned)TOPKN) {
                sel[0] = base + k;
                sel[1] = (int)(running - h);
                break;
            }
        }
    }
}

// compact all anchors with bucket >= B into keys[]; key = (score_bits<<32)|~a
// -> descending key order == (score desc, idx asc) == stable top_k order.
__global__ void compact_kernel(const float* __restrict__ scores, int* sel,
                               unsigned long long* __restrict__ keys) {
    int a = blockIdx.x * blockDim.x + threadIdx.x;
    if (a >= N_ANCH) return;
    float s = scores[a];
    if (s < 0.0f) return;
    unsigned bits = __float_as_uint(s);
    if ((int)(bits >> 16) < sel[0]) return;
    int pos = atomicAdd(&sel[2], 1);
    if (pos < KCAP) keys[pos] = ((unsigned long long)bits << 32) | (unsigned)(~a);
}

// exact rank by counting: rank[i] = #{j : key_j > key_i}. Keys unique ->
// ranks are a permutation; ranks 0..4095 are the sorted top-4096.
// Grid: (KCAP/256 row-blocks) x (NCOLP column parts). Column tiles of 2048
// keys staged in LDS; all lanes read the same tile[j] -> broadcast, no
// bank conflicts.
constexpr int NCOLP = 4;
__global__ void rank_kernel(const unsigned long long* __restrict__ keys,
                            const int* __restrict__ sel, int* __restrict__ rank) {
    __shared__ unsigned long long tile[2048];
    int n = sel[2]; if (n > KCAP) n = KCAP;
    int i = blockIdx.x * 256 + threadIdx.x;
    unsigned long long myKey = (i < n) ? keys[i] : 0ull;
    int cnt = 0;
    for (int t0 = blockIdx.y * 2048; t0 < n; t0 += 2048 * NCOLP) {
        int m = n - t0; if (m > 2048) m = 2048;
        for (int j = threadIdx.x; j < m; j += 256) tile[j] = keys[t0 + j];
        __syncthreads();
        int j = 0;
        for (; j + 3 < m; j += 4) {
            cnt += (tile[j]     > myKey);
            cnt += (tile[j + 1] > myKey);
            cnt += (tile[j + 2] > myKey);
            cnt += (tile[j + 3] > myKey);
        }
        for (; j < m; ++j) cnt += (tile[j] > myKey);
        __syncthreads();
    }
    if (i < n && cnt < TOPKN) atomicAdd(&rank[i], cnt);
}

// place keys by rank; also decode the yxyx box for the sorted slot (no fma).
__global__ void scatter_kernel(const float* __restrict__ x,
                               const unsigned long long* __restrict__ keys,
                               const int* __restrict__ sel, const int* __restrict__ rank,
                               int* __restrict__ sidx, float* __restrict__ sscore,
                               float* __restrict__ boxes) {
    int n = sel[2]; if (n > KCAP) n = KCAP;
    int i = blockIdx.x * 256 + threadIdx.x;
    if (i >= n) return;
    int r = rank[i];
    if (r >= TOPKN) return;
    unsigned long long k = keys[i];
    int a = (int)(~(unsigned)(k & 0xFFFFFFFFull));
    sidx[r]   = a;
    sscore[r] = __uint_as_float((unsigned)(k >> 32));
    const float* p = x + (size_t)a * DIMV;
    float xc = p[0], yc = p[1], w = p[2], h = p[3];
    float hw = __fmul_rn(w, 0.5f);
    float hh = __fmul_rn(h, 0.5f);
    boxes[r * 4 + 0] = __fsub_rn(yc, hh);
    boxes[r * 4 + 1] = __fsub_rn(xc, hw);
    boxes[r * 4 + 2] = __fadd_rn(yc, hh);
    boxes[r * 4 + 3] = __fadd_rn(xc, hw);
}

// 64x64 tile IoU bitmask: bit j of mask[r][colT] set iff iou(r, colT*64+j)>0.45 && j_global>r
__global__ void iou_mask_kernel(const float* __restrict__ boxes,
                                unsigned long long* __restrict__ mask) {
    int colT = blockIdx.x, rowT = blockIdx.y;
    int t = threadIdx.x;                 // 0..63
    int r = rowT * 64 + t;
    if (colT < rowT) {                   // whole tile has j < r
        mask[(size_t)r * 64 + colT] = 0ull;
        return;
    }
    __shared__ float cb[64][5];
    int cj = colT * 64 + t;
    {
        float y1 = boxes[cj * 4 + 0], x1 = boxes[cj * 4 + 1];
        float y2 = boxes[cj * 4 + 2], x2 = boxes[cj * 4 + 3];
        cb[t][0] = y1; cb[t][1] = x1; cb[t][2] = y2; cb[t][3] = x2;
        cb[t][4] = __fmul_rn(__fsub_rn(y2, y1), __fsub_rn(x2, x1));
    }
    __syncthreads();
    float ry1 = boxes[r * 4 + 0], rx1 = boxes[r * 4 + 1];
    float ry2 = boxes[r * 4 + 2], rx2 = boxes[r * 4 + 3];
    float rarea = __fmul_rn(__fsub_rn(ry2, ry1), __fsub_rn(rx2, rx1));
    unsigned long long bitsw = 0ull;
#pragma unroll 8
    for (int j = 0; j < 64; ++j) {
        float iy1 = fmaxf(ry1, cb[j][0]);
        float ix1 = fmaxf(rx1, cb[j][1]);
        float iy2 = fminf(ry2, cb[j][2]);
        float ix2 = fminf(rx2, cb[j][3]);
        float ih = fmaxf(__fsub_rn(iy2, iy1), 0.0f);
        float iw = fmaxf(__fsub_rn(ix2, ix1), 0.0f);
        float inter = __fmul_rn(ih, iw);
        float uni = __fsub_rn(__fadd_rn(rarea, cb[j][4]), inter);
        float iou = __fdiv_rn(inter, fmaxf(uni, 1e-9f));
        if (iou > 0.45f && (colT * 64 + j) > r) bitsw |= (1ull << j);
    }
    mask[(size_t)r * 64 + colT] = bitsw;
}

// single-wave sequential greedy scan. lane j owns suppression word j.
// Early-exit at 300 keeps (exact: output is the first 300 kept rows).
// If K<300, pad with lowest-index suppressed rows at score -1 (== stable
// top_k of where(keep, s, -1)).
__global__ void nms_scan_kernel(const unsigned long long* __restrict__ mask,
                                const float* __restrict__ sscore,
                                int* __restrict__ outIdx, float* __restrict__ outScore) {
    int lane = threadIdx.x;              // 64 threads = one wave
    unsigned long long remv = 0ull;
    __shared__ int keepArr[MAXDET];
    __shared__ unsigned long long remvFinal[64];
    int count = 0;
    for (int w = 0; w < 64 && count < MAXDET; ++w) {
        unsigned long long cur = __shfl(remv, w);
        int pos = 0;
        while (pos < 64) {
            unsigned long long avail = (~cur) & (~0ull << pos);
            if (!avail) break;
            int b = (int)__builtin_ctzll(avail);
            int i = (w << 6) + b;
            if (lane == 0) keepArr[count] = i;
            count++;
            if (count >= MAXDET) break;
            remv |= mask[(size_t)i * 64 + lane];
            cur = __shfl(remv, w);
            pos = b + 1;
        }
    }
    remvFinal[lane] = remv;
    __syncthreads();
    int K = count;                       // uniform across the wave
    for (int k = lane; k < K; k += 64) {
        int s = keepArr[k];
        outIdx[k] = s;
        outScore[k] = sscore[s];
    }
    if (K < MAXDET && lane == 0) {
        int filled = K;
        for (int w = 0; w < 64 && filled < MAXDET; ++w) {
            unsigned long long word = remvFinal[w];
            while (word && filled < MAXDET) {
                int b = (int)__builtin_ctzll(word);
                word &= word - 1;
                outIdx[filled] = (w << 6) + b;
                outScore[filled] = -1.0f;
                filled++;
            }
        }
    }
}

// emit: boxes[300*4] | classes[300] | scores[300] | masks[300*32]
__global__ void write_out_kernel(const float* __restrict__ x, const int* __restrict__ sidx,
                                 const int* __restrict__ cls, const float* __restrict__ boxes,
                                 const int* __restrict__ outIdx, const float* __restrict__ outScore,
                                 float* __restrict__ out) {
    int o = blockIdx.x;                  // 300
    int t = threadIdx.x;                 // 64
    int s = outIdx[o];
    int a = sidx[s];
    if (t < 32) {
        out[1800 + o * 32 + t] = x[(size_t)a * DIMV + 85 + t];
    } else if (t < 36) {
        out[o * 4 + (t - 32)] = boxes[s * 4 + (t - 32)];
    } else if (t == 36) {
        out[1200 + o] = (float)cls[a];
    } else if (t == 37) {
        out[1500 + o] = outScore[o];
    }
}

extern "C" void kernel_launch(void* const* d_in, const int* in_sizes, int n_in,
                              void* d_out, int out_size, void* d_ws, size_t ws_size,
                              hipStream_t stream) {
    const float* x = (const float*)d_in[0];
    char* ws = (char*)d_ws;
    unsigned*            hist   = (unsigned*)(ws + WS_HIST);
    float*               scores = (float*)(ws + WS_SCORES);
    int*                 cls    = (int*)(ws + WS_CLS);
    int*                 sel    = (int*)(ws + WS_SEL);
    unsigned long long*  keys   = (unsigned long long*)(ws + WS_KEYS);
    int*                 rank   = (int*)(ws + WS_RANK);
    int*                 sidx   = (int*)(ws + WS_SIDX);
    float*               sscore = (float*)(ws + WS_SSC);
    float*               boxes  = (float*)(ws + WS_BOXES);
    unsigned long long*  mask   = (unsigned long long*)(ws + WS_MASK);
    int*                 outIdx = (int*)(ws + WS_OUTI);
    float*               outSc  = (float*)(ws + WS_OUTS);

    zero_kernel<<<(65536 + 255) / 256, 256, 0, stream>>>(hist, sel, rank);
    score_kernel<<<(N_ANCH + 255) / 256, 256, 0, stream>>>(x, scores, cls, hist);
    select_kernel<<<1, 1024, 0, stream>>>(hist, sel);
    compact_kernel<<<(N_ANCH + 255) / 256, 256, 0, stream>>>(scores, sel, keys);
    dim3 rg(KCAP / 256, NCOLP);
    rank_kernel<<<rg, 256, 0, stream>>>(keys, sel, rank);
    scatter_kernel<<<KCAP / 256, 256, 0, stream>>>(x, keys, sel, rank, sidx, sscore, boxes);
    dim3 mg(64, 64);
    iou_mask_kernel<<<mg, 64, 0, stream>>>(boxes, mask);
    nms_scan_kernel<<<1, 64, 0, stream>>>(mask, sscore, outIdx, outSc);
    write_out_kernel<<<MAXDET, 64, 0, stream>>>(x, sidx, cls, boxes, outIdx, outSc, (float*)d_out);
}

// Round 3
// 322.404 us; speedup vs baseline: 1.2708x; 1.0330x over previous
//
#include <hip/hip_runtime.h>

// ---------------------------------------------------------------------------
// YOLO NMS post-processing for MI355X.
// Pipeline: scores (LDS-staged, 2 thr/row) + hist -> bucket select -> compact
// candidates (bucket >= B) -> exact rank-by-counting -> scatter by rank (+box
// decode) -> 64x64 IoU bitmask -> batched-speculative single-wave greedy scan
// (32 mask rows prefetched per batch; decide chain is register-only) -> gather.
// All IoU-relevant fp32 math uses _rn intrinsics so hipcc's default
// -ffp-contract=fast cannot fuse mul+add into fma (must match numpy fp32).
// ---------------------------------------------------------------------------

constexpr int    N_ANCH = 100800;
constexpr int    DIMV   = 117;   // 4 box + 1 obj + 80 cls + 32 mask
constexpr int    NCLS   = 80;
constexpr int    TOPKN  = 4096;
constexpr int    MAXDET = 300;
constexpr int    KCAP   = 12288; // candidate capacity (expected ~4096+|bucket B|)

// workspace layout (bytes)
constexpr size_t WS_HIST   = 0;                           // 65536 u32
constexpr size_t WS_SCORES = WS_HIST   + 65536ull * 4;    // 100800 f32
constexpr size_t WS_CLS    = WS_SCORES + 100800ull * 4;   // 100800 i32
constexpr size_t WS_SEL    = WS_CLS    + 100800ull * 4;   // 64 i32: [0]=B [1]=cntAbove [2]=nKeys
constexpr size_t WS_KEYS   = WS_SEL    + 256;             // 12288 u64
constexpr size_t WS_RANK   = WS_KEYS   + (size_t)KCAP * 8;// 12288 i32
constexpr size_t WS_SIDX   = WS_RANK   + (size_t)KCAP * 4;// 4096 i32 (anchor id / sorted slot)
constexpr size_t WS_SSC    = WS_SIDX   + 4096ull * 4;     // 4096 f32 (sorted scores desc)
constexpr size_t WS_BOXES  = WS_SSC    + 4096ull * 4;     // 4096*4 f32 (y1 x1 y2 x2)
constexpr size_t WS_MASK   = WS_BOXES  + 4096ull * 16;    // 4096*64 u64 suppression bitmask
constexpr size_t WS_OUTI   = WS_MASK   + 4096ull * 64 * 8;// 300 i32
constexpr size_t WS_OUTS   = WS_OUTI   + 1200;            // 300 f32

__global__ void zero_kernel(unsigned* __restrict__ hist, int* __restrict__ sel,
                            int* __restrict__ rank) {
    int i = blockIdx.x * blockDim.x + threadIdx.x;
    if (i < 65536) hist[i] = 0u;
    if (i < KCAP)  rank[i] = 0;
    if (i < 64)    sel[i]  = 0;
}

// 64 rows per 128-thread block, staged to LDS with coalesced float4 loads.
// 2 threads per row: even lane scans classes 0..39, odd lane 40..79, merged
// via shfl_xor. Strict > keeps the first (lowest-class) argmax like numpy.
constexpr int SROWS = 64;
__global__ void score_kernel(const float* __restrict__ x, float* __restrict__ scores,
                             int* __restrict__ cls, unsigned* __restrict__ hist) {
    __shared__ float sx[SROWS * DIMV];           // 29952 B
    int block0 = blockIdx.x * SROWS;
    const float4* src = (const float4*)(x + (size_t)block0 * DIMV); // 64*468 % 16 == 0
    float4* dst = (float4*)sx;
    constexpr int NV4 = SROWS * DIMV / 4;        // 1872
    for (int i = threadIdx.x; i < NV4; i += 128) dst[i] = src[i];
    __syncthreads();
    int row  = threadIdx.x >> 1;
    int half = threadIdx.x & 1;
    const float* rp = sx + row * DIMV;
    float obj = rp[4];
    const float* cp = rp + 5 + half * 40;
    float best = -1.0f;
    int   bc   = half * 40;
#pragma unroll 8
    for (int c = 0; c < 40; ++c) {
        float s = __fmul_rn(cp[c], obj);
        if (s > best) { best = s; bc = half * 40 + c; }
    }
    float so = __shfl_xor(best, 1);
    int   co = __shfl_xor(bc, 1);
    if (half == 0) {
        if (so > best) { best = so; bc = co; }   // strict >: even (lower classes) wins ties
        int a = block0 + row;
        bool valid = obj > 0.25f;
        scores[a] = valid ? best : -1.0f;
        cls[a]    = bc;
        if (valid) atomicAdd(&hist[__float_as_uint(best) >> 16], 1u);
    }
}

// find bucket B: cntAbove(B) < 4096 <= cntAbove(B) + hist[B].
__global__ void select_kernel(const unsigned* __restrict__ hist, int* sel) {
    __shared__ unsigned sv[1024];
    int t = threadIdx.x;
    int base = 65536 - 64 * (t + 1);          // chunk t covers [base, base+63], t=0 = top
    unsigned own = 0;
#pragma unroll 8
    for (int k = 0; k < 64; ++k) own += hist[base + k];
    sv[t] = own;
    __syncthreads();
    for (int off = 1; off < 1024; off <<= 1) { // inclusive scan (descending-chunk order)
        unsigned v = (t >= off) ? sv[t - off] : 0u;
        __syncthreads();
        sv[t] += v;
        __syncthreads();
    }
    unsigned incl = sv[t];
    unsigned before = incl - own;
    if (before < (unsigned)TOPKN && incl >= (unsigned)TOPKN) {
        unsigned running = before;
        for (int k = 63; k >= 0; --k) {        // walk buckets descending
            unsigned h = hist[base + k];
            running += h;
            if (running >= (unsigned)TOPKN) {
                sel[0] = base + k;
                sel[1] = (int)(running - h);
                break;
            }
        }
    }
}

// compact all anchors with bucket >= B into keys[]; key = (score_bits<<32)|~a
// -> descending key order == (score desc, idx asc) == stable top_k order.
__global__ void compact_kernel(const float* __restrict__ scores, int* sel,
                               unsigned long long* __restrict__ keys) {
    int a = blockIdx.x * blockDim.x + threadIdx.x;
    if (a >= N_ANCH) return;
    float s = scores[a];
    if (s < 0.0f) return;
    unsigned bits = __float_as_uint(s);
    if ((int)(bits >> 16) < sel[0]) return;
    int pos = atomicAdd(&sel[2], 1);
    if (pos < KCAP) keys[pos] = ((unsigned long long)bits << 32) | (unsigned)(~a);
}

// exact rank by counting: rank[i] = #{j : key_j > key_i}. Keys unique ->
// ranks are a permutation; ranks 0..4095 are the sorted top-4096.
constexpr int NCOLP = 4;
__global__ void rank_kernel(const unsigned long long* __restrict__ keys,
                            const int* __restrict__ sel, int* __restrict__ rank) {
    __shared__ unsigned long long tile[2048];
    int n = sel[2]; if (n > KCAP) n = KCAP;
    int i = blockIdx.x * 256 + threadIdx.x;
    unsigned long long myKey = (i < n) ? keys[i] : 0ull;
    int cnt = 0;
    for (int t0 = blockIdx.y * 2048; t0 < n; t0 += 2048 * NCOLP) {
        int m = n - t0; if (m > 2048) m = 2048;
        for (int j = threadIdx.x; j < m; j += 256) tile[j] = keys[t0 + j];
        __syncthreads();
        int j = 0;
        for (; j + 3 < m; j += 4) {
            cnt += (tile[j]     > myKey);
            cnt += (tile[j + 1] > myKey);
            cnt += (tile[j + 2] > myKey);
            cnt += (tile[j + 3] > myKey);
        }
        for (; j < m; ++j) cnt += (tile[j] > myKey);
        __syncthreads();
    }
    if (i < n && cnt < TOPKN) atomicAdd(&rank[i], cnt);
}

// place keys by rank; also decode the yxyx box for the sorted slot (no fma).
__global__ void scatter_kernel(const float* __restrict__ x,
                               const unsigned long long* __restrict__ keys,
                               const int* __restrict__ sel, const int* __restrict__ rank,
                               int* __restrict__ sidx, float* __restrict__ sscore,
                               float* __restrict__ boxes) {
    int n = sel[2]; if (n > KCAP) n = KCAP;
    int i = blockIdx.x * 256 + threadIdx.x;
    if (i >= n) return;
    int r = rank[i];
    if (r >= TOPKN) return;
    unsigned long long k = keys[i];
    int a = (int)(~(unsigned)(k & 0xFFFFFFFFull));
    sidx[r]   = a;
    sscore[r] = __uint_as_float((unsigned)(k >> 32));
    const float* p = x + (size_t)a * DIMV;
    float xc = p[0], yc = p[1], w = p[2], h = p[3];
    float hw = __fmul_rn(w, 0.5f);
    float hh = __fmul_rn(h, 0.5f);
    boxes[r * 4 + 0] = __fsub_rn(yc, hh);
    boxes[r * 4 + 1] = __fsub_rn(xc, hw);
    boxes[r * 4 + 2] = __fadd_rn(yc, hh);
    boxes[r * 4 + 3] = __fadd_rn(xc, hw);
}

// 64x64 tile IoU bitmask: bit j of mask[r][colT] set iff iou(r, colT*64+j)>0.45 && j_global>r
__global__ void iou_mask_kernel(const float* __restrict__ boxes,
                                unsigned long long* __restrict__ mask) {
    int colT = blockIdx.x, rowT = blockIdx.y;
    int t = threadIdx.x;                 // 0..63
    int r = rowT * 64 + t;
    if (colT < rowT) {                   // whole tile has j < r
        mask[(size_t)r * 64 + colT] = 0ull;
        return;
    }
    __shared__ float cb[64][5];
    int cj = colT * 64 + t;
    {
        float y1 = boxes[cj * 4 + 0], x1 = boxes[cj * 4 + 1];
        float y2 = boxes[cj * 4 + 2], x2 = boxes[cj * 4 + 3];
        cb[t][0] = y1; cb[t][1] = x1; cb[t][2] = y2; cb[t][3] = x2;
        cb[t][4] = __fmul_rn(__fsub_rn(y2, y1), __fsub_rn(x2, x1));
    }
    __syncthreads();
    float ry1 = boxes[r * 4 + 0], rx1 = boxes[r * 4 + 1];
    float ry2 = boxes[r * 4 + 2], rx2 = boxes[r * 4 + 3];
    float rarea = __fmul_rn(__fsub_rn(ry2, ry1), __fsub_rn(rx2, rx1));
    unsigned long long bitsw = 0ull;
#pragma unroll 8
    for (int j = 0; j < 64; ++j) {
        float iy1 = fmaxf(ry1, cb[j][0]);
        float ix1 = fmaxf(rx1, cb[j][1]);
        float iy2 = fminf(ry2, cb[j][2]);
        float ix2 = fminf(rx2, cb[j][3]);
        float ih = fmaxf(__fsub_rn(iy2, iy1), 0.0f);
        float iw = fmaxf(__fsub_rn(ix2, ix1), 0.0f);
        float inter = __fmul_rn(ih, iw);
        float uni = __fsub_rn(__fadd_rn(rarea, cb[j][4]), inter);
        float iou = __fdiv_rn(inter, fmaxf(uni, 1e-9f));
        if (iou > 0.45f && (colT * 64 + j) > r) bitsw |= (1ull << j);
    }
    mask[(size_t)r * 64 + colT] = bitsw;
}

// Batched speculative greedy scan (single wave). lane j owns remv word j.
// Each batch: enumerate next BATCH currently-alive rows, load their mask rows
// in parallel into VGPRs (one latency round-trip), then decide sequentially
// with register-only ops. remv only grows, so the alive set at enumeration is
// a superset of the true alive set -- suppressed-in-batch rows are re-checked
// and skipped. Early-exit at 300 keeps; padding = lowest-index suppressed.
__global__ void nms_scan_kernel(const unsigned long long* __restrict__ mask,
                                const float* __restrict__ sscore,
                                int* __restrict__ outIdx, float* __restrict__ outScore) {
    constexpr int BATCH = 32;
    int lane = threadIdx.x;              // 64 threads = one wave
    unsigned long long remv = 0ull;
    __shared__ int list[BATCH];
    __shared__ int keepArr[MAXDET];
    __shared__ unsigned long long remvFinal[64];
    int count = 0;
    int pos = 0;                          // first undecided row
    while (count < MAXDET && pos < TOPKN) {
        // --- enumerate next BATCH alive rows starting at pos ---
        unsigned long long avail = ~remv;
        int w0 = pos >> 6;
        if (lane < w0) avail = 0ull;
        else if (lane == w0) avail &= (~0ull) << (pos & 63);
        int cnt = __popcll(avail);
        int pre = cnt;                    // inclusive prefix over lanes
        for (int off = 1; off < 64; off <<= 1) {
            int v = __shfl_up(pre, off);
            if (lane >= off) pre += v;
        }
        int total = __shfl(pre, 63);
        pre -= cnt;                       // exclusive
        unsigned long long a = avail;
        int slot = pre;
        while (a && slot < BATCH) {
            int b = (int)__builtin_ctzll(a);
            a &= a - 1;
            list[slot] = (lane << 6) + b;
            slot++;
        }
        __syncthreads();
        int nb = (total < BATCH) ? total : BATCH;
        if (nb == 0) break;
        // --- parallel load of the nb candidate mask rows (clamped, branchless)
        int rows[BATCH];
        unsigned long long m[BATCH];
#pragma unroll
        for (int k = 0; k < BATCH; ++k) {
            int kk = (k < nb) ? k : nb - 1;
            rows[k] = list[kk];
        }
#pragma unroll
        for (int k = 0; k < BATCH; ++k) {
            m[k] = mask[(size_t)rows[k] * 64 + lane];
        }
        // --- sequential decide (register-only chain) ---
        int lastRow = rows[0];
#pragma unroll
        for (int k = 0; k < BATCH; ++k) {
            if (k < nb && count < MAXDET) {
                int r = rows[k];
                lastRow = r;
                unsigned long long cur = __shfl(remv, r >> 6);
                if (!((cur >> (r & 63)) & 1ull)) {     // still alive -> keep
                    if (lane == 0) keepArr[count] = r;
                    count++;
                    remv |= m[k];
                }
            }
        }
        pos = lastRow + 1;
        __syncthreads();                  // protect list[] reuse
    }
    remvFinal[lane] = remv;
    __syncthreads();
    int K = count;                        // uniform across the wave
    for (int k = lane; k < K; k += 64) {
        int s = keepArr[k];
        outIdx[k] = s;
        outScore[k] = sscore[s];
    }
    if (K < MAXDET && lane == 0) {
        int filled = K;
        for (int w = 0; w < 64 && filled < MAXDET; ++w) {
            unsigned long long word = remvFinal[w];
            while (word && filled < MAXDET) {
                int b = (int)__builtin_ctzll(word);
                word &= word - 1;
                outIdx[filled] = (w << 6) + b;
                outScore[filled] = -1.0f;
                filled++;
            }
        }
    }
}

// emit: boxes[300*4] | classes[300] | scores[300] | masks[300*32]
__global__ void write_out_kernel(const float* __restrict__ x, const int* __restrict__ sidx,
                                 const int* __restrict__ cls, const float* __restrict__ boxes,
                                 const int* __restrict__ outIdx, const float* __restrict__ outScore,
                                 float* __restrict__ out) {
    int o = blockIdx.x;                  // 300
    int t = threadIdx.x;                 // 64
    int s = outIdx[o];
    int a = sidx[s];
    if (t < 32) {
        out[1800 + o * 32 + t] = x[(size_t)a * DIMV + 85 + t];
    } else if (t < 36) {
        out[o * 4 + (t - 32)] = boxes[s * 4 + (t - 32)];
    } else if (t == 36) {
        out[1200 + o] = (float)cls[a];
    } else if (t == 37) {
        out[1500 + o] = outScore[o];
    }
}

extern "C" void kernel_launch(void* const* d_in, const int* in_sizes, int n_in,
                              void* d_out, int out_size, void* d_ws, size_t ws_size,
                              hipStream_t stream) {
    const float* x = (const float*)d_in[0];
    char* ws = (char*)d_ws;
    unsigned*            hist   = (unsigned*)(ws + WS_HIST);
    float*               scores = (float*)(ws + WS_SCORES);
    int*                 cls    = (int*)(ws + WS_CLS);
    int*                 sel    = (int*)(ws + WS_SEL);
    unsigned long long*  keys   = (unsigned long long*)(ws + WS_KEYS);
    int*                 rank   = (int*)(ws + WS_RANK);
    int*                 sidx   = (int*)(ws + WS_SIDX);
    float*               sscore = (float*)(ws + WS_SSC);
    float*               boxes  = (float*)(ws + WS_BOXES);
    unsigned long long*  mask   = (unsigned long long*)(ws + WS_MASK);
    int*                 outIdx = (int*)(ws + WS_OUTI);
    float*               outSc  = (float*)(ws + WS_OUTS);

    zero_kernel<<<(65536 + 255) / 256, 256, 0, stream>>>(hist, sel, rank);
    score_kernel<<<N_ANCH / SROWS, 128, 0, stream>>>(x, scores, cls, hist);
    select_kernel<<<1, 1024, 0, stream>>>(hist, sel);
    compact_kernel<<<(N_ANCH + 255) / 256, 256, 0, stream>>>(scores, sel, keys);
    dim3 rg(KCAP / 256, NCOLP);
    rank_kernel<<<rg, 256, 0, stream>>>(keys, sel, rank);
    scatter_kernel<<<KCAP / 256, 256, 0, stream>>>(x, keys, sel, rank, sidx, sscore, boxes);
    dim3 mg(64, 64);
    iou_mask_kernel<<<mg, 64, 0, stream>>>(boxes, mask);
    nms_scan_kernel<<<1, 64, 0, stream>>>(mask, sscore, outIdx, outSc);
    write_out_kernel<<<MAXDET, 64, 0, stream>>>(x, sidx, cls, boxes, outIdx, outSc, (float*)d_out);
}

// Round 4
// 288.728 us; speedup vs baseline: 1.4190x; 1.1166x over previous
//
#include <hip/hip_runtime.h>

// ---------------------------------------------------------------------------
// YOLO NMS post-processing for MI355X.
// Pipeline: scores (LDS-staged, 2 thr/row) + hist -> bucket select -> compact
// candidates (bucket >= B) -> exact rank-by-counting -> scatter by rank (+box
// decode) -> 64x64 IoU bitmask -> batched-speculative single-wave greedy scan
// (64 mask rows prefetched per batch into REGISTERS -- __launch_bounds__(64,1)
// so the batch array does NOT spill; decide chain is ballot-based) -> gather.
// All IoU-relevant fp32 math uses _rn intrinsics so hipcc's default
// -ffp-contract=fast cannot fuse mul+add into fma (must match numpy fp32).
// ---------------------------------------------------------------------------

constexpr int    N_ANCH = 100800;
constexpr int    DIMV   = 117;   // 4 box + 1 obj + 80 cls + 32 mask
constexpr int    NCLS   = 80;
constexpr int    TOPKN  = 4096;
constexpr int    MAXDET = 300;
constexpr int    KCAP   = 12288; // candidate capacity (expected ~4096+|bucket B|)

// workspace layout (bytes)
constexpr size_t WS_HIST   = 0;                           // 65536 u32
constexpr size_t WS_SCORES = WS_HIST   + 65536ull * 4;    // 100800 f32
constexpr size_t WS_CLS    = WS_SCORES + 100800ull * 4;   // 100800 i32
constexpr size_t WS_SEL    = WS_CLS    + 100800ull * 4;   // 64 i32: [0]=B [1]=cntAbove [2]=nKeys
constexpr size_t WS_KEYS   = WS_SEL    + 256;             // 12288 u64
constexpr size_t WS_RANK   = WS_KEYS   + (size_t)KCAP * 8;// 12288 i32
constexpr size_t WS_SIDX   = WS_RANK   + (size_t)KCAP * 4;// 4096 i32 (anchor id / sorted slot)
constexpr size_t WS_SSC    = WS_SIDX   + 4096ull * 4;     // 4096 f32 (sorted scores desc)
constexpr size_t WS_BOXES  = WS_SSC    + 4096ull * 4;     // 4096*4 f32 (y1 x1 y2 x2)
constexpr size_t WS_MASK   = WS_BOXES  + 4096ull * 16;    // 4096*64 u64 suppression bitmask
constexpr size_t WS_OUTI   = WS_MASK   + 4096ull * 64 * 8;// 300 i32
constexpr size_t WS_OUTS   = WS_OUTI   + 1200;            // 300 f32

__global__ void zero_kernel(unsigned* __restrict__ hist, int* __restrict__ sel,
                            int* __restrict__ rank) {
    int i = blockIdx.x * blockDim.x + threadIdx.x;
    if (i < 65536) hist[i] = 0u;
    if (i < KCAP)  rank[i] = 0;
    if (i < 64)    sel[i]  = 0;
}

// 64 rows per 128-thread block, staged to LDS with coalesced float4 loads.
// 2 threads per row: even lane scans classes 0..39, odd lane 40..79, merged
// via shfl_xor. Strict > keeps the first (lowest-class) argmax like numpy.
constexpr int SROWS = 64;
__global__ void score_kernel(const float* __restrict__ x, float* __restrict__ scores,
                             int* __restrict__ cls, unsigned* __restrict__ hist) {
    __shared__ float sx[SROWS * DIMV];           // 29952 B
    int block0 = blockIdx.x * SROWS;
    const float4* src = (const float4*)(x + (size_t)block0 * DIMV); // 64*468 % 16 == 0
    float4* dst = (float4*)sx;
    constexpr int NV4 = SROWS * DIMV / 4;        // 1872
    for (int i = threadIdx.x; i < NV4; i += 128) dst[i] = src[i];
    __syncthreads();
    int row  = threadIdx.x >> 1;
    int half = threadIdx.x & 1;
    const float* rp = sx + row * DIMV;
    float obj = rp[4];
    const float* cp = rp + 5 + half * 40;
    float best = -1.0f;
    int   bc   = half * 40;
#pragma unroll 8
    for (int c = 0; c < 40; ++c) {
        float s = __fmul_rn(cp[c], obj);
        if (s > best) { best = s; bc = half * 40 + c; }
    }
    float so = __shfl_xor(best, 1);
    int   co = __shfl_xor(bc, 1);
    if (half == 0) {
        if (so > best) { best = so; bc = co; }   // strict >: even (lower classes) wins ties
        int a = block0 + row;
        bool valid = obj > 0.25f;
        scores[a] = valid ? best : -1.0f;
        cls[a]    = bc;
        if (valid) atomicAdd(&hist[__float_as_uint(best) >> 16], 1u);
    }
}

// find bucket B: cntAbove(B) < 4096 <= cntAbove(B) + hist[B].
// Thread t sums its 64-bucket chunk with uint4 loads (16 independent 16B
// loads -> pipelined), one 1024-scan, crossing thread walks its chunk.
__global__ void select_kernel(const unsigned* __restrict__ hist, int* sel) {
    __shared__ unsigned sv[1024];
    int t = threadIdx.x;
    int base = 65536 - 64 * (t + 1);          // chunk t covers [base, base+63], t=0 = top
    const uint4* hp = (const uint4*)(hist + base);
    unsigned own = 0;
#pragma unroll
    for (int k = 0; k < 16; ++k) {
        uint4 v = hp[k];
        own += v.x + v.y + v.z + v.w;
    }
    sv[t] = own;
    __syncthreads();
    for (int off = 1; off < 1024; off <<= 1) { // inclusive scan (descending-chunk order)
        unsigned v = (t >= off) ? sv[t - off] : 0u;
        __syncthreads();
        sv[t] += v;
        __syncthreads();
    }
    unsigned incl = sv[t];
    unsigned before = incl - own;
    if (before < (unsigned)TOPKN && incl >= (unsigned)TOPKN) {
        unsigned running = before;
        for (int k = 63; k >= 0; --k) {        // walk buckets descending
            unsigned h = hist[base + k];
            running += h;
            if (running >= (unsigned)TOPKN) {
                sel[0] = base + k;
                sel[1] = (int)(running - h);
                break;
            }
        }
    }
}

// compact all anchors with bucket >= B into keys[]; key = (score_bits<<32)|~a
// -> descending key order == (score desc, idx asc) == stable top_k order.
__global__ void compact_kernel(const float* __restrict__ scores, int* sel,
                               unsigned long long* __restrict__ keys) {
    int a = blockIdx.x * blockDim.x + threadIdx.x;
    if (a >= N_ANCH) return;
    float s = scores[a];
    if (s < 0.0f) return;
    unsigned bits = __float_as_uint(s);
    if ((int)(bits >> 16) < sel[0]) return;
    int pos = atomicAdd(&sel[2], 1);
    if (pos < KCAP) keys[pos] = ((unsigned long long)bits << 32) | (unsigned)(~a);
}

// exact rank by counting: rank[i] = #{j : key_j > key_i}. Keys unique ->
// ranks are a permutation; ranks 0..4095 are the sorted top-4096.
constexpr int NCOLP = 4;
__global__ void rank_kernel(const unsigned long long* __restrict__ keys,
                            const int* __restrict__ sel, int* __restrict__ rank) {
    __shared__ unsigned long long tile[2048];
    int n = sel[2]; if (n > KCAP) n = KCAP;
    int i = blockIdx.x * 256 + threadIdx.x;
    unsigned long long myKey = (i < n) ? keys[i] : 0ull;
    int cnt = 0;
    for (int t0 = blockIdx.y * 2048; t0 < n; t0 += 2048 * NCOLP) {
        int m = n - t0; if (m > 2048) m = 2048;
        for (int j = threadIdx.x; j < m; j += 256) tile[j] = keys[t0 + j];
        __syncthreads();
        int j = 0;
        for (; j + 3 < m; j += 4) {
            cnt += (tile[j]     > myKey);
            cnt += (tile[j + 1] > myKey);
            cnt += (tile[j + 2] > myKey);
            cnt += (tile[j + 3] > myKey);
        }
        for (; j < m; ++j) cnt += (tile[j] > myKey);
        __syncthreads();
    }
    if (i < n && cnt < TOPKN) atomicAdd(&rank[i], cnt);
}

// place keys by rank; also decode the yxyx box for the sorted slot (no fma).
__global__ void scatter_kernel(const float* __restrict__ x,
                               const unsigned long long* __restrict__ keys,
                               const int* __restrict__ sel, const int* __restrict__ rank,
                               int* __restrict__ sidx, float* __restrict__ sscore,
                               float* __restrict__ boxes) {
    int n = sel[2]; if (n > KCAP) n = KCAP;
    int i = blockIdx.x * 256 + threadIdx.x;
    if (i >= n) return;
    int r = rank[i];
    if (r >= TOPKN) return;
    unsigned long long k = keys[i];
    int a = (int)(~(unsigned)(k & 0xFFFFFFFFull));
    sidx[r]   = a;
    sscore[r] = __uint_as_float((unsigned)(k >> 32));
    const float* p = x + (size_t)a * DIMV;
    float xc = p[0], yc = p[1], w = p[2], h = p[3];
    float hw = __fmul_rn(w, 0.5f);
    float hh = __fmul_rn(h, 0.5f);
    boxes[r * 4 + 0] = __fsub_rn(yc, hh);
    boxes[r * 4 + 1] = __fsub_rn(xc, hw);
    boxes[r * 4 + 2] = __fadd_rn(yc, hh);
    boxes[r * 4 + 3] = __fadd_rn(xc, hw);
}

// 64x64 tile IoU bitmask: bit j of mask[r][colT] set iff iou(r, colT*64+j)>0.45 && j_global>r
__global__ void iou_mask_kernel(const float* __restrict__ boxes,
                                unsigned long long* __restrict__ mask) {
    int colT = blockIdx.x, rowT = blockIdx.y;
    int t = threadIdx.x;                 // 0..63
    int r = rowT * 64 + t;
    if (colT < rowT) {                   // whole tile has j < r
        mask[(size_t)r * 64 + colT] = 0ull;
        return;
    }
    __shared__ float cb[64][5];
    int cj = colT * 64 + t;
    {
        float y1 = boxes[cj * 4 + 0], x1 = boxes[cj * 4 + 1];
        float y2 = boxes[cj * 4 + 2], x2 = boxes[cj * 4 + 3];
        cb[t][0] = y1; cb[t][1] = x1; cb[t][2] = y2; cb[t][3] = x2;
        cb[t][4] = __fmul_rn(__fsub_rn(y2, y1), __fsub_rn(x2, x1));
    }
    __syncthreads();
    float ry1 = boxes[r * 4 + 0], rx1 = boxes[r * 4 + 1];
    float ry2 = boxes[r * 4 + 2], rx2 = boxes[r * 4 + 3];
    float rarea = __fmul_rn(__fsub_rn(ry2, ry1), __fsub_rn(rx2, rx1));
    unsigned long long bitsw = 0ull;
#pragma unroll 8
    for (int j = 0; j < 64; ++j) {
        float iy1 = fmaxf(ry1, cb[j][0]);
        float ix1 = fmaxf(rx1, cb[j][1]);
        float iy2 = fminf(ry2, cb[j][2]);
        float ix2 = fminf(rx2, cb[j][3]);
        float ih = fmaxf(__fsub_rn(iy2, iy1), 0.0f);
        float iw = fmaxf(__fsub_rn(ix2, ix1), 0.0f);
        float inter = __fmul_rn(ih, iw);
        float uni = __fsub_rn(__fadd_rn(rarea, cb[j][4]), inter);
        float iou = __fdiv_rn(inter, fmaxf(uni, 1e-9f));
        if (iou > 0.45f && (colT * 64 + j) > r) bitsw |= (1ull << j);
    }
    mask[(size_t)r * 64 + colT] = bitsw;
}

// Batched speculative greedy scan (single wave). lane j owns remv word j.
// __launch_bounds__(64,1): one wave/SIMD -> ~450 VGPRs available, so the
// 64-row batch (m[64]=128 VGPRs) stays in registers -- all 64 loads of a
// batch are in flight concurrently (one latency round-trip per batch).
// Decide chain uses __ballot (1 v_cmp + sgpr extract per step) instead of
// 64-bit shfl. remv only grows, so enumerated-alive is a superset of
// true-alive; suppressed-in-batch rows are re-checked and skipped.
__global__ void __launch_bounds__(64, 1)
nms_scan_kernel(const unsigned long long* __restrict__ mask,
                const float* __restrict__ sscore,
                int* __restrict__ outIdx, float* __restrict__ outScore) {
    constexpr int BATCH = 64;
    int lane = threadIdx.x;              // 64 threads = one wave
    unsigned long long remv = 0ull;
    __shared__ int list[BATCH];
    __shared__ int keepArr[MAXDET];
    __shared__ unsigned long long remvFinal[64];
    int count = 0;
    int pos = 0;                          // first undecided row
    while (count < MAXDET && pos < TOPKN) {
        // --- enumerate next BATCH alive rows starting at pos ---
        unsigned long long avail = ~remv;
        int w0 = pos >> 6;
        if (lane < w0) avail = 0ull;
        else if (lane == w0) avail &= (~0ull) << (pos & 63);
        int cnt = __popcll(avail);
        int pre = cnt;                    // inclusive prefix over lanes
        for (int off = 1; off < 64; off <<= 1) {
            int v = __shfl_up(pre, off);
            if (lane >= off) pre += v;
        }
        int total = __shfl(pre, 63);
        pre -= cnt;                       // exclusive
        unsigned long long a = avail;
        int slot = pre;
        while (a && slot < BATCH) {
            int b = (int)__builtin_ctzll(a);
            a &= a - 1;
            list[slot] = (lane << 6) + b;
            slot++;
        }
        __syncthreads();
        int nb = (total < BATCH) ? total : BATCH;
        if (nb == 0) break;
        // --- parallel load of the nb candidate mask rows into registers ---
        int rows[BATCH];
        unsigned long long m[BATCH];
#pragma unroll
        for (int k = 0; k < BATCH; ++k) {
            if (k < nb) rows[k] = list[k];
        }
#pragma unroll
        for (int k = 0; k < BATCH; ++k) {
            if (k < nb) m[k] = mask[(size_t)rows[k] * 64 + lane];
        }
        // --- sequential decide (ballot-based, register-only chain) ---
        int lastRow = list[0];
#pragma unroll
        for (int k = 0; k < BATCH; ++k) {
            if (k < nb && count < MAXDET) {
                int r = rows[k];
                lastRow = r;
                unsigned long long bal = __ballot(((remv >> (r & 63)) & 1ull) != 0);
                if (!((bal >> (r >> 6)) & 1ull)) {     // still alive -> keep
                    if (lane == 0) keepArr[count] = r;
                    count++;
                    remv |= m[k];
                }
            }
        }
        pos = lastRow + 1;
        __syncthreads();                  // protect list[] reuse
    }
    remvFinal[lane] = remv;
    __syncthreads();
    int K = count;                        // uniform across the wave
    for (int k = lane; k < K; k += 64) {
        int s = keepArr[k];
        outIdx[k] = s;
        outScore[k] = sscore[s];
    }
    if (K < MAXDET && lane == 0) {
        int filled = K;
        for (int w = 0; w < 64 && filled < MAXDET; ++w) {
            unsigned long long word = remvFinal[w];
            while (word && filled < MAXDET) {
                int b = (int)__builtin_ctzll(word);
                word &= word - 1;
                outIdx[filled] = (w << 6) + b;
                outScore[filled] = -1.0f;
                filled++;
            }
        }
    }
}

// emit: boxes[300*4] | classes[300] | scores[300] | masks[300*32]
__global__ void write_out_kernel(const float* __restrict__ x, const int* __restrict__ sidx,
                                 const int* __restrict__ cls, const float* __restrict__ boxes,
                                 const int* __restrict__ outIdx, const float* __restrict__ outScore,
                                 float* __restrict__ out) {
    int o = blockIdx.x;                  // 300
    int t = threadIdx.x;                 // 64
    int s = outIdx[o];
    int a = sidx[s];
    if (t < 32) {
        out[1800 + o * 32 + t] = x[(size_t)a * DIMV + 85 + t];
    } else if (t < 36) {
        out[o * 4 + (t - 32)] = boxes[s * 4 + (t - 32)];
    } else if (t == 36) {
        out[1200 + o] = (float)cls[a];
    } else if (t == 37) {
        out[1500 + o] = outScore[o];
    }
}

extern "C" void kernel_launch(void* const* d_in, const int* in_sizes, int n_in,
                              void* d_out, int out_size, void* d_ws, size_t ws_size,
                              hipStream_t stream) {
    const float* x = (const float*)d_in[0];
    char* ws = (char*)d_ws;
    unsigned*            hist   = (unsigned*)(ws + WS_HIST);
    float*               scores = (float*)(ws + WS_SCORES);
    int*                 cls    = (int*)(ws + WS_CLS);
    int*                 sel    = (int*)(ws + WS_SEL);
    unsigned long long*  keys   = (unsigned long long*)(ws + WS_KEYS);
    int*                 rank   = (int*)(ws + WS_RANK);
    int*                 sidx   = (int*)(ws + WS_SIDX);
    float*               sscore = (float*)(ws + WS_SSC);
    float*               boxes  = (float*)(ws + WS_BOXES);
    unsigned long long*  mask   = (unsigned long long*)(ws + WS_MASK);
    int*                 outIdx = (int*)(ws + WS_OUTI);
    float*               outSc  = (float*)(ws + WS_OUTS);

    zero_kernel<<<(65536 + 255) / 256, 256, 0, stream>>>(hist, sel, rank);
    score_kernel<<<N_ANCH / SROWS, 128, 0, stream>>>(x, scores, cls, hist);
    select_kernel<<<1, 1024, 0, stream>>>(hist, sel);
    compact_kernel<<<(N_ANCH + 255) / 256, 256, 0, stream>>>(scores, sel, keys);
    dim3 rg(KCAP / 256, NCOLP);
    rank_kernel<<<rg, 256, 0, stream>>>(keys, sel, rank);
    scatter_kernel<<<KCAP / 256, 256, 0, stream>>>(x, keys, sel, rank, sidx, sscore, boxes);
    dim3 mg(64, 64);
    iou_mask_kernel<<<mg, 64, 0, stream>>>(boxes, mask);
    nms_scan_kernel<<<1, 64, 0, stream>>>(mask, sscore, outIdx, outSc);
    write_out_kernel<<<MAXDET, 64, 0, stream>>>(x, sidx, cls, boxes, outIdx, outSc, (float*)d_out);
}

// Round 5
// 232.149 us; speedup vs baseline: 1.7648x; 1.2437x over previous
//
#include <hip/hip_runtime.h>

// ---------------------------------------------------------------------------
// YOLO NMS post-processing for MI355X.
// Pipeline: scores (LDS-staged, 2 thr/row) + 32-way sliced histogram (kills
// device-atomic hot-line contention; slices overlay the not-yet-used mask
// buffer) -> reduce slices -> bucket select -> compact candidates (bucket >=
// B) -> exact rank-by-counting -> scatter by rank (+box decode) -> 64x64 IoU
// bitmask (overwrites the slice region) -> batched-speculative single-wave
// greedy scan (64 rows prefetched into registers, __launch_bounds__(64,1) so
// no spill) -> gather outputs.
// All IoU-relevant fp32 math uses _rn intrinsics so hipcc's default
// -ffp-contract=fast cannot fuse mul+add into fma (must match numpy fp32).
// ---------------------------------------------------------------------------

constexpr int    N_ANCH = 100800;
constexpr int    DIMV   = 117;   // 4 box + 1 obj + 80 cls + 32 mask
constexpr int    NCLS   = 80;
constexpr int    TOPKN  = 4096;
constexpr int    MAXDET = 300;
constexpr int    KCAP   = 12288; // candidate capacity
constexpr int    NBUCK  = 16384; // scores < 1.0 -> bits>>16 < 0x3F80 < 16384
constexpr int    NSLICE = 32;

// workspace layout (bytes)
constexpr size_t WS_HIST   = 0;                           // 16384 u32 (final hist)
constexpr size_t WS_SCORES = WS_HIST   + 65536ull * 4;    // 100800 f32
constexpr size_t WS_CLS    = WS_SCORES + 100800ull * 4;   // 100800 i32
constexpr size_t WS_SEL    = WS_CLS    + 100800ull * 4;   // 64 i32: [0]=B [1]=cntAbove [2]=nKeys
constexpr size_t WS_KEYS   = WS_SEL    + 256;             // 12288 u64
constexpr size_t WS_RANK   = WS_KEYS   + (size_t)KCAP * 8;// 12288 i32
constexpr size_t WS_SIDX   = WS_RANK   + (size_t)KCAP * 4;// 4096 i32 (anchor id / sorted slot)
constexpr size_t WS_SSC    = WS_SIDX   + 4096ull * 4;     // 4096 f32 (sorted scores desc)
constexpr size_t WS_BOXES  = WS_SSC    + 4096ull * 4;     // 4096*4 f32 (y1 x1 y2 x2)
constexpr size_t WS_MASK   = WS_BOXES  + 4096ull * 16;    // 4096*64 u64 mask; BEFORE iou_mask
                                                          // runs, the SAME 2 MB holds the
                                                          // 32x16384 u32 hist slices (exact fit)
constexpr size_t WS_OUTI   = WS_MASK   + 4096ull * 64 * 8;// 300 i32
constexpr size_t WS_OUTS   = WS_OUTI   + 1200;            // 300 f32

__global__ void zero_kernel(unsigned* __restrict__ slices, int* __restrict__ sel,
                            int* __restrict__ rank) {
    int i = blockIdx.x * blockDim.x + threadIdx.x;
    if (i < NSLICE * NBUCK) slices[i] = 0u;
    if (i < KCAP)           rank[i]  = 0;
    if (i < 64)             sel[i]   = 0;
}

// 64 rows per 128-thread block, staged to LDS with coalesced float4 loads.
// 2 threads per row: even lane scans classes 0..39, odd lane 40..79, merged
// via shfl_xor. Strict > keeps the first (lowest-class) argmax like numpy.
// Histogram atomics go to slice (blockIdx & 31) to spread hot-line contention.
constexpr int SROWS = 64;
__global__ void score_kernel(const float* __restrict__ x, float* __restrict__ scores,
                             int* __restrict__ cls, unsigned* __restrict__ slices) {
    __shared__ float sx[SROWS * DIMV];           // 29952 B
    int block0 = blockIdx.x * SROWS;
    const float4* src = (const float4*)(x + (size_t)block0 * DIMV); // 64*468 % 16 == 0
    float4* dst = (float4*)sx;
    constexpr int NV4 = SROWS * DIMV / 4;        // 1872
    for (int i = threadIdx.x; i < NV4; i += 128) dst[i] = src[i];
    __syncthreads();
    int row  = threadIdx.x >> 1;
    int half = threadIdx.x & 1;
    const float* rp = sx + row * DIMV;
    float obj = rp[4];
    const float* cp = rp + 5 + half * 40;
    float best = -1.0f;
    int   bc   = half * 40;
#pragma unroll 8
    for (int c = 0; c < 40; ++c) {
        float s = __fmul_rn(cp[c], obj);
        if (s > best) { best = s; bc = half * 40 + c; }
    }
    float so = __shfl_xor(best, 1);
    int   co = __shfl_xor(bc, 1);
    if (half == 0) {
        if (so > best) { best = so; bc = co; }   // strict >: even (lower classes) wins ties
        int a = block0 + row;
        bool valid = obj > 0.25f;
        scores[a] = valid ? best : -1.0f;
        cls[a]    = bc;
        if (valid) {
            unsigned b = __float_as_uint(best) >> 16;   // < 16384 (best in [0,1))
            atomicAdd(&slices[(blockIdx.x & (NSLICE - 1)) * NBUCK + b], 1u);
        }
    }
}

// fold 32 slices into the final histogram. 64 blocks x 256 threads.
__global__ void reduce_hist_kernel(const unsigned* __restrict__ slices,
                                   unsigned* __restrict__ hist) {
    int b = blockIdx.x * 256 + threadIdx.x;
    unsigned s = 0;
#pragma unroll
    for (int k = 0; k < NSLICE; ++k) s += slices[k * NBUCK + b];
    hist[b] = s;
}

// find bucket B: cntAbove(B) < 4096 <= cntAbove(B) + hist[B].
// Thread t sums its 16-bucket chunk (descending order), one 1024-scan,
// crossing thread walks its chunk.
__global__ void select_kernel(const unsigned* __restrict__ hist, int* sel) {
    __shared__ unsigned sv[1024];
    int t = threadIdx.x;
    int base = NBUCK - 16 * (t + 1);          // chunk t covers [base, base+15], t=0 = top
    const uint4* hp = (const uint4*)(hist + base);
    unsigned own = 0;
#pragma unroll
    for (int k = 0; k < 4; ++k) {
        uint4 v = hp[k];
        own += v.x + v.y + v.z + v.w;
    }
    sv[t] = own;
    __syncthreads();
    for (int off = 1; off < 1024; off <<= 1) { // inclusive scan (descending-chunk order)
        unsigned v = (t >= off) ? sv[t - off] : 0u;
        __syncthreads();
        sv[t] += v;
        __syncthreads();
    }
    unsigned incl = sv[t];
    unsigned before = incl - own;
    if (before < (unsigned)TOPKN && incl >= (unsigned)TOPKN) {
        unsigned running = before;
        for (int k = 15; k >= 0; --k) {        // walk buckets descending
            unsigned h = hist[base + k];
            running += h;
            if (running >= (unsigned)TOPKN) {
                sel[0] = base + k;
                sel[1] = (int)(running - h);
                break;
            }
        }
    }
}

// compact all anchors with bucket >= B into keys[]; key = (score_bits<<32)|~a
// -> descending key order == (score desc, idx asc) == stable top_k order.
__global__ void compact_kernel(const float* __restrict__ scores, int* sel,
                               unsigned long long* __restrict__ keys) {
    int a = blockIdx.x * blockDim.x + threadIdx.x;
    if (a >= N_ANCH) return;
    float s = scores[a];
    if (s < 0.0f) return;
    unsigned bits = __float_as_uint(s);
    if ((int)(bits >> 16) < sel[0]) return;
    int pos = atomicAdd(&sel[2], 1);
    if (pos < KCAP) keys[pos] = ((unsigned long long)bits << 32) | (unsigned)(~a);
}

// exact rank by counting: rank[i] = #{j : key_j > key_i}. Keys unique ->
// ranks are a permutation; ranks 0..4095 are the sorted top-4096.
constexpr int NCOLP = 4;
__global__ void rank_kernel(const unsigned long long* __restrict__ keys,
                            const int* __restrict__ sel, int* __restrict__ rank) {
    __shared__ unsigned long long tile[2048];
    int n = sel[2]; if (n > KCAP) n = KCAP;
    int i = blockIdx.x * 256 + threadIdx.x;
    unsigned long long myKey = (i < n) ? keys[i] : 0ull;
    int cnt = 0;
    for (int t0 = blockIdx.y * 2048; t0 < n; t0 += 2048 * NCOLP) {
        int m = n - t0; if (m > 2048) m = 2048;
        for (int j = threadIdx.x; j < m; j += 256) tile[j] = keys[t0 + j];
        __syncthreads();
        int j = 0;
        for (; j + 3 < m; j += 4) {
            cnt += (tile[j]     > myKey);
            cnt += (tile[j + 1] > myKey);
            cnt += (tile[j + 2] > myKey);
            cnt += (tile[j + 3] > myKey);
        }
        for (; j < m; ++j) cnt += (tile[j] > myKey);
        __syncthreads();
    }
    if (i < n && cnt < TOPKN) atomicAdd(&rank[i], cnt);
}

// place keys by rank; also decode the yxyx box for the sorted slot (no fma).
__global__ void scatter_kernel(const float* __restrict__ x,
                               const unsigned long long* __restrict__ keys,
                               const int* __restrict__ sel, const int* __restrict__ rank,
                               int* __restrict__ sidx, float* __restrict__ sscore,
                               float* __restrict__ boxes) {
    int n = sel[2]; if (n > KCAP) n = KCAP;
    int i = blockIdx.x * 256 + threadIdx.x;
    if (i >= n) return;
    int r = rank[i];
    if (r >= TOPKN) return;
    unsigned long long k = keys[i];
    int a = (int)(~(unsigned)(k & 0xFFFFFFFFull));
    sidx[r]   = a;
    sscore[r] = __uint_as_float((unsigned)(k >> 32));
    const float* p = x + (size_t)a * DIMV;
    float xc = p[0], yc = p[1], w = p[2], h = p[3];
    float hw = __fmul_rn(w, 0.5f);
    float hh = __fmul_rn(h, 0.5f);
    boxes[r * 4 + 0] = __fsub_rn(yc, hh);
    boxes[r * 4 + 1] = __fsub_rn(xc, hw);
    boxes[r * 4 + 2] = __fadd_rn(yc, hh);
    boxes[r * 4 + 3] = __fadd_rn(xc, hw);
}

// 64x64 tile IoU bitmask: bit j of mask[r][colT] set iff iou(r, colT*64+j)>0.45 && j_global>r
__global__ void iou_mask_kernel(const float* __restrict__ boxes,
                                unsigned long long* __restrict__ mask) {
    int colT = blockIdx.x, rowT = blockIdx.y;
    int t = threadIdx.x;                 // 0..63
    int r = rowT * 64 + t;
    if (colT < rowT) {                   // whole tile has j < r
        mask[(size_t)r * 64 + colT] = 0ull;
        return;
    }
    __shared__ float cb[64][5];
    int cj = colT * 64 + t;
    {
        float y1 = boxes[cj * 4 + 0], x1 = boxes[cj * 4 + 1];
        float y2 = boxes[cj * 4 + 2], x2 = boxes[cj * 4 + 3];
        cb[t][0] = y1; cb[t][1] = x1; cb[t][2] = y2; cb[t][3] = x2;
        cb[t][4] = __fmul_rn(__fsub_rn(y2, y1), __fsub_rn(x2, x1));
    }
    __syncthreads();
    float ry1 = boxes[r * 4 + 0], rx1 = boxes[r * 4 + 1];
    float ry2 = boxes[r * 4 + 2], rx2 = boxes[r * 4 + 3];
    float rarea = __fmul_rn(__fsub_rn(ry2, ry1), __fsub_rn(rx2, rx1));
    unsigned long long bitsw = 0ull;
#pragma unroll 8
    for (int j = 0; j < 64; ++j) {
        float iy1 = fmaxf(ry1, cb[j][0]);
        float ix1 = fmaxf(rx1, cb[j][1]);
        float iy2 = fminf(ry2, cb[j][2]);
        float ix2 = fminf(rx2, cb[j][3]);
        float ih = fmaxf(__fsub_rn(iy2, iy1), 0.0f);
        float iw = fmaxf(__fsub_rn(ix2, ix1), 0.0f);
        float inter = __fmul_rn(ih, iw);
        float uni = __fsub_rn(__fadd_rn(rarea, cb[j][4]), inter);
        float iou = __fdiv_rn(inter, fmaxf(uni, 1e-9f));
        if (iou > 0.45f && (colT * 64 + j) > r) bitsw |= (1ull << j);
    }
    mask[(size_t)r * 64 + colT] = bitsw;
}

// Batched speculative greedy scan (single wave). lane j owns remv word j.
// __launch_bounds__(64,1): one wave/SIMD -> ~450 VGPRs, so the 64-row batch
// (m[64]=128 VGPRs) stays in registers; all 64 loads of a batch are in flight
// concurrently. Decide chain uses __ballot. remv only grows, so
// enumerated-alive is a superset of true-alive; stale rows are re-checked.
__global__ void __launch_bounds__(64, 1)
nms_scan_kernel(const unsigned long long* __restrict__ mask,
                const float* __restrict__ sscore,
                int* __restrict__ outIdx, float* __restrict__ outScore) {
    constexpr int BATCH = 64;
    int lane = threadIdx.x;              // 64 threads = one wave
    unsigned long long remv = 0ull;
    __shared__ int list[BATCH];
    __shared__ int keepArr[MAXDET];
    __shared__ unsigned long long remvFinal[64];
    int count = 0;
    int pos = 0;                          // first undecided row
    while (count < MAXDET && pos < TOPKN) {
        // --- enumerate next BATCH alive rows starting at pos ---
        unsigned long long avail = ~remv;
        int w0 = pos >> 6;
        if (lane < w0) avail = 0ull;
        else if (lane == w0) avail &= (~0ull) << (pos & 63);
        int cnt = __popcll(avail);
        int pre = cnt;                    // inclusive prefix over lanes
        for (int off = 1; off < 64; off <<= 1) {
            int v = __shfl_up(pre, off);
            if (lane >= off) pre += v;
        }
        int total = __shfl(pre, 63);
        pre -= cnt;                       // exclusive
        unsigned long long a = avail;
        int slot = pre;
        while (a && slot < BATCH) {
            int b = (int)__builtin_ctzll(a);
            a &= a - 1;
            list[slot] = (lane << 6) + b;
            slot++;
        }
        __syncthreads();
        int nb = (total < BATCH) ? total : BATCH;
        if (nb == 0) break;
        // --- parallel load of the nb candidate mask rows into registers ---
        int rows[BATCH];
        unsigned long long m[BATCH];
#pragma unroll
        for (int k = 0; k < BATCH; ++k) {
            if (k < nb) rows[k] = list[k];
        }
#pragma unroll
        for (int k = 0; k < BATCH; ++k) {
            if (k < nb) m[k] = mask[(size_t)rows[k] * 64 + lane];
        }
        // --- sequential decide (ballot-based, register-only chain) ---
        int lastRow = list[0];
#pragma unroll
        for (int k = 0; k < BATCH; ++k) {
            if (k < nb && count < MAXDET) {
                int r = rows[k];
                lastRow = r;
                unsigned long long bal = __ballot(((remv >> (r & 63)) & 1ull) != 0);
                if (!((bal >> (r >> 6)) & 1ull)) {     // still alive -> keep
                    if (lane == 0) keepArr[count] = r;
                    count++;
                    remv |= m[k];
                }
            }
        }
        pos = lastRow + 1;
        __syncthreads();                  // protect list[] reuse
    }
    remvFinal[lane] = remv;
    __syncthreads();
    int K = count;                        // uniform across the wave
    for (int k = lane; k < K; k += 64) {
        int s = keepArr[k];
        outIdx[k] = s;
        outScore[k] = sscore[s];
    }
    if (K < MAXDET && lane == 0) {
        int filled = K;
        for (int w = 0; w < 64 && filled < MAXDET; ++w) {
            unsigned long long word = remvFinal[w];
            while (word && filled < MAXDET) {
                int b = (int)__builtin_ctzll(word);
                word &= word - 1;
                outIdx[filled] = (w << 6) + b;
                outScore[filled] = -1.0f;
                filled++;
            }
        }
    }
}

// emit: boxes[300*4] | classes[300] | scores[300] | masks[300*32]
__global__ void write_out_kernel(const float* __restrict__ x, const int* __restrict__ sidx,
                                 const int* __restrict__ cls, const float* __restrict__ boxes,
                                 const int* __restrict__ outIdx, const float* __restrict__ outScore,
                                 float* __restrict__ out) {
    int o = blockIdx.x;                  // 300
    int t = threadIdx.x;                 // 64
    int s = outIdx[o];
    int a = sidx[s];
    if (t < 32) {
        out[1800 + o * 32 + t] = x[(size_t)a * DIMV + 85 + t];
    } else if (t < 36) {
        out[o * 4 + (t - 32)] = boxes[s * 4 + (t - 32)];
    } else if (t == 36) {
        out[1200 + o] = (float)cls[a];
    } else if (t == 37) {
        out[1500 + o] = outScore[o];
    }
}

extern "C" void kernel_launch(void* const* d_in, const int* in_sizes, int n_in,
                              void* d_out, int out_size, void* d_ws, size_t ws_size,
                              hipStream_t stream) {
    const float* x = (const float*)d_in[0];
    char* ws = (char*)d_ws;
    unsigned*            hist   = (unsigned*)(ws + WS_HIST);
    float*               scores = (float*)(ws + WS_SCORES);
    int*                 cls    = (int*)(ws + WS_CLS);
    int*                 sel    = (int*)(ws + WS_SEL);
    unsigned long long*  keys   = (unsigned long long*)(ws + WS_KEYS);
    int*                 rank   = (int*)(ws + WS_RANK);
    int*                 sidx   = (int*)(ws + WS_SIDX);
    float*               sscore = (float*)(ws + WS_SSC);
    float*               boxes  = (float*)(ws + WS_BOXES);
    unsigned long long*  mask   = (unsigned long long*)(ws + WS_MASK);
    unsigned*            slices = (unsigned*)(ws + WS_MASK);  // overlay: dead before iou_mask
    int*                 outIdx = (int*)(ws + WS_OUTI);
    float*               outSc  = (float*)(ws + WS_OUTS);

    zero_kernel<<<(NSLICE * NBUCK + 255) / 256, 256, 0, stream>>>(slices, sel, rank);
    score_kernel<<<N_ANCH / SROWS, 128, 0, stream>>>(x, scores, cls, slices);
    reduce_hist_kernel<<<NBUCK / 256, 256, 0, stream>>>(slices, hist);
    select_kernel<<<1, 1024, 0, stream>>>(hist, sel);
    compact_kernel<<<(N_ANCH + 255) / 256, 256, 0, stream>>>(scores, sel, keys);
    dim3 rg(KCAP / 256, NCOLP);
    rank_kernel<<<rg, 256, 0, stream>>>(keys, sel, rank);
    scatter_kernel<<<KCAP / 256, 256, 0, stream>>>(x, keys, sel, rank, sidx, sscore, boxes);
    dim3 mg(64, 64);
    iou_mask_kernel<<<mg, 64, 0, stream>>>(boxes, mask);
    nms_scan_kernel<<<1, 64, 0, stream>>>(mask, sscore, outIdx, outSc);
    write_out_kernel<<<MAXDET, 64, 0, stream>>>(x, sidx, cls, boxes, outIdx, outSc, (float*)d_out);
}